// Round 7
// baseline (77290.173 us; speedup 1.0000x reference)
//
#include <hip/hip_runtime.h>
#include <math.h>

#define NWG 256
#define NTH 512

// agent-coherent (L2-bypassing) scalar access — the cross-XCD exchange primitive
__device__ __forceinline__ float cload(const float* p) {
    return __hip_atomic_load(p, __ATOMIC_RELAXED, __HIP_MEMORY_SCOPE_AGENT);
}
__device__ __forceinline__ void cstore(float* p, float v) {
    __hip_atomic_store(p, v, __ATOMIC_RELAXED, __HIP_MEMORY_SCOPE_AGENT);
}

__global__ void k_zero(unsigned* p, int n) {
    int i = blockIdx.x * 256 + threadIdx.x;
    if (i < n) p[i] = 0u;
}

// transpose x [64][512][16] -> xT [512][64][16] (float4 granularity)
__global__ void k_xt(const float* __restrict__ x, float* __restrict__ xT) {
    int i = blockIdx.x * 256 + threadIdx.x;
    if (i < 131072) {
        int mt = i >> 2, q = i & 3;
        int m = mt >> 9, t = mt & 511;
        float4 v = *(const float4*)(x + (size_t)i * 4);
        *(float4*)(xT + ((size_t)t * 64 + m) * 16 + q * 4) = v;
    }
}

// One persistent cooperative kernel. WG w owns h-columns c0=2w, c0+1 of BOTH
// layers (6 gate-rows per matrix), lane = chain. Pipeline at slot s:
//   h0(s) | gi1(s-1)+h1(s-1) | FC(s-2) | biophys -> theta(s-3)
// h buffers: k-major [k][chain] parity double-buffers, accessed ONLY via
// agent-coherent loads/stores. NO per-thread array larger than 16 floats
// (h1r[64] spilled to scratch in R4-R6 -> 105 GB of WRITE traffic; chunked
// streaming keeps everything in VGPRs).
__global__ __launch_bounds__(NTH)
void k_fused(const float* __restrict__ xT,
             const float* __restrict__ Wih0, const float* __restrict__ Whh0,
             const float* __restrict__ bih0, const float* __restrict__ bhh0,
             const float* __restrict__ Wih1, const float* __restrict__ Whh1,
             const float* __restrict__ bih1, const float* __restrict__ bhh1,
             const float* __restrict__ fcW, const float* __restrict__ fcb,
             const float* __restrict__ h0in, const float* __restrict__ th0,
             const float* __restrict__ om0, float* __restrict__ out,
             float* __restrict__ h0buf, float* __restrict__ h1buf,
             float* __restrict__ apre_g, unsigned* __restrict__ bar)
{
    const int w = blockIdx.x, tid = threadIdx.x;
    const int v = tid >> 6, m = tid & 63;
    const int c0 = w * 2;
    const int ks = v * 64;
    __shared__ float w0s[6 * 512];   // Whh0 rows (local g = gate*2 + j)
    __shared__ float wi1s[6 * 512];  // Wih1 rows
    __shared__ float w1s[6 * 512];   // Whh1 rows
    __shared__ float wihs[6 * 16];   // Wih0 rows
    __shared__ float fcrow[512];     // this WG's fc row (WGs 8..23)
    __shared__ float pl[8 * 12 * 64];
    __shared__ float pl2[8 * 64];

    for (int i = tid; i < 6 * 128; i += NTH) {
        int g = i >> 7, q = (i & 127) * 4;
        int row = (g >> 1) * 512 + c0 + (g & 1);
        *(float4*)&w0s[g * 512 + q]  = *(const float4*)(Whh0 + (size_t)row * 512 + q);
        *(float4*)&wi1s[g * 512 + q] = *(const float4*)(Wih1 + (size_t)row * 512 + q);
        *(float4*)&w1s[g * 512 + q]  = *(const float4*)(Whh1 + (size_t)row * 512 + q);
    }
    if (tid < 24) {
        int g = tid >> 2, q = (tid & 3) * 4;
        int row = (g >> 1) * 512 + c0 + (g & 1);
        *(float4*)&wihs[g * 16 + q] = *(const float4*)(Wih0 + (size_t)row * 16 + q);
    }
    const bool isFC = (w >= 8 && w < 24);
    if (isFC && tid < 128)
        *(float4*)&fcrow[tid * 4] = *(const float4*)(fcW + (size_t)(w - 8) * 512 + tid * 4);

    float b_r0=0,b_z0=0,b_in0=0,b_hn0=0, bi1r=0,bi1z=0,bi1n=0, bh1r=0,bh1z=0,bh1n=0;
    if (v < 2) {
        int c = c0 + v;
        b_r0  = bih0[c] + bhh0[c];
        b_z0  = bih0[512 + c] + bhh0[512 + c];
        b_in0 = bih0[1024 + c]; b_hn0 = bhh0[1024 + c];
        bi1r = bih1[c]; bi1z = bih1[512 + c]; bi1n = bih1[1024 + c];
        bh1r = bhh1[c]; bh1z = bhh1[512 + c]; bh1n = bhh1[1024 + c];
    }
    // biophys state: WG 0, thread = chain*8 + joint
    float th = 0.f, om = 0.f, fb0 = 0.f, fb1 = 0.f;
    if (w == 0) {
        th = th0[tid]; om = om0[tid];
        fb0 = fcb[2 * (tid & 7)]; fb1 = fcb[2 * (tid & 7) + 1];
    }
    const float* h1in = h0in + 32768;
    float gi_r = 0.f, gi_z = 0.f, gi_n = 0.f;
    __syncthreads();

    for (int s = 0; s < 515; ++s) {
        const int pw0 = s & 1, pr0 = (s + 1) & 1;
        // ---- biophys: consume apre written last slot -> theta(s-3) ----
        if (w == 0 && s >= 3) {
            int mc = tid >> 3, j = tid & 7;
            const float* ap = apre_g + ((s + 1) & 1) * 1024;
            float a0 = 1.f / (1.f + expf(-(cload(&ap[(2 * j) * 64 + mc]) + fb0)));
            float a1 = 1.f / (1.f + expf(-(cload(&ap[(2 * j + 1) * 64 + mc]) + fb1)));
            float F0 = (100.f + 2000.f * a0) * (0.06f + 0.006f * a0 + 0.05f * th);
            float F1 = (100.f + 2000.f * a1) * (0.06f + 0.006f * a1 - 0.05f * th);
            float tau = 0.05f * (F1 - F0);
            float acc = (tau - 5.f * th - 0.3f * om) * 250.f;
            om += (1.f / 60.f) * acc;
            th += (1.f / 60.f) * om;
            out[((size_t)mc * 512 + (s - 3)) * 8 + j] = th;
        }
        // ---- fused phase 1+2: Whh0 & Wih1 dots over h0(s-1) ----
        if (s <= 512) {
            float a01[12];
            #pragma unroll
            for (int g = 0; g < 12; ++g) a01[g] = 0.f;
            #pragma unroll
            for (int kb = 0; kb < 4; ++kb) {
                float hb[16];
                if (s == 0) {
                    #pragma unroll
                    for (int q = 0; q < 4; ++q) {
                        float4 t = *(const float4*)(h0in + (size_t)m * 512 + ks + kb * 16 + q * 4);
                        hb[q*4] = t.x; hb[q*4+1] = t.y; hb[q*4+2] = t.z; hb[q*4+3] = t.w;
                    }
                } else {
                    const float* hp = h0buf + pr0 * 32768 + (ks + kb * 16) * 64 + m;
                    #pragma unroll
                    for (int i = 0; i < 16; ++i) hb[i] = cload(&hp[i * 64]);
                }
                #pragma unroll
                for (int i = 0; i < 16; ++i) {
                    float hv = hb[i];
                    int ko = ks + kb * 16 + i;
                    #pragma unroll
                    for (int g = 0; g < 6; ++g) {
                        a01[g]     += w0s[g * 512 + ko] * hv;
                        a01[6 + g] += wi1s[g * 512 + ko] * hv;
                    }
                }
            }
            #pragma unroll
            for (int g = 0; g < 12; ++g) pl[(v * 12 + g) * 64 + m] = a01[g];
        }
        __syncthreads();
        // ---- combine A: h0(s) update + gi1(s-1) registers ----
        if (v < 2) {
            int c = c0 + v;
            if (s <= 511) {
                float hr = 0.f, hz = 0.f, hn = 0.f;
                #pragma unroll
                for (int u = 0; u < 8; ++u) {
                    hr += pl[(u * 12 + v) * 64 + m];
                    hz += pl[(u * 12 + 2 + v) * 64 + m];
                    hn += pl[(u * 12 + 4 + v) * 64 + m];
                }
                const float* xp = xT + ((size_t)s * 64 + m) * 16;
                float ir = 0.f, iz = 0.f, in_ = 0.f;
                #pragma unroll
                for (int k = 0; k < 16; ++k) {
                    float xv = xp[k];
                    ir  += wihs[v * 16 + k] * xv;
                    iz  += wihs[(2 + v) * 16 + k] * xv;
                    in_ += wihs[(4 + v) * 16 + k] * xv;
                }
                float hold = (s == 0) ? h0in[(size_t)m * 512 + c]
                                      : cload(&h0buf[pr0 * 32768 + c * 64 + m]);
                float r = 1.f / (1.f + expf(-(ir + hr + b_r0)));
                float z = 1.f / (1.f + expf(-(iz + hz + b_z0)));
                float n = tanhf(in_ + b_in0 + r * (hn + b_hn0));
                cstore(&h0buf[pw0 * 32768 + c * 64 + m], (1.f - z) * n + z * hold);
            }
            if (s >= 1 && s <= 512) {
                gi_r = bi1r; gi_z = bi1z; gi_n = bi1n;
                #pragma unroll
                for (int u = 0; u < 8; ++u) {
                    gi_r += pl[(u * 12 + 6 + v) * 64 + m];
                    gi_z += pl[(u * 12 + 8 + v) * 64 + m];
                    gi_n += pl[(u * 12 + 10 + v) * 64 + m];
                }
            }
        }
        __syncthreads();
        // ---- phase 3: Whh1 dot over h1(s-2) + FC dot, streamed in 16-chunks ----
        if (s >= 1 && s <= 513) {
            float a2[6];
            #pragma unroll
            for (int g = 0; g < 6; ++g) a2[g] = 0.f;
            float fdot = 0.f;
            #pragma unroll
            for (int kb = 0; kb < 4; ++kb) {
                float hb[16];
                if (s == 1) {
                    #pragma unroll
                    for (int q = 0; q < 4; ++q) {
                        float4 t = *(const float4*)(h1in + (size_t)m * 512 + ks + kb * 16 + q * 4);
                        hb[q*4] = t.x; hb[q*4+1] = t.y; hb[q*4+2] = t.z; hb[q*4+3] = t.w;
                    }
                } else {
                    const float* hp = h1buf + (s & 1) * 32768 + (ks + kb * 16) * 64 + m;
                    #pragma unroll
                    for (int i = 0; i < 16; ++i) hb[i] = cload(&hp[i * 64]);
                }
                #pragma unroll
                for (int i = 0; i < 16; ++i) {
                    float hv = hb[i];
                    int ko = ks + kb * 16 + i;
                    #pragma unroll
                    for (int g = 0; g < 6; ++g) a2[g] += w1s[g * 512 + ko] * hv;
                    fdot += hv * fcrow[ko];
                }
            }
            if (s <= 512) {
                #pragma unroll
                for (int g = 0; g < 6; ++g) pl[(v * 12 + g) * 64 + m] = a2[g];
            }
            if (isFC && s >= 2) pl2[v * 64 + m] = fdot;
        }
        __syncthreads();
        // ---- combine B: h1(s-1) update ----
        if (s >= 1 && s <= 512 && v < 2) {
            int c = c0 + v;
            float hr = 0.f, hz = 0.f, hn = 0.f;
            #pragma unroll
            for (int u = 0; u < 8; ++u) {
                hr += pl[(u * 12 + v) * 64 + m];
                hz += pl[(u * 12 + 2 + v) * 64 + m];
                hn += pl[(u * 12 + 4 + v) * 64 + m];
            }
            float hold = (s == 1) ? h1in[(size_t)m * 512 + c]
                                  : cload(&h1buf[(s & 1) * 32768 + c * 64 + m]);
            float r = 1.f / (1.f + expf(-(gi_r + hr + bh1r)));
            float z = 1.f / (1.f + expf(-(gi_z + hz + bh1z)));
            float n = tanhf(gi_n + r * (hn + bh1n));
            cstore(&h1buf[((s + 1) & 1) * 32768 + c * 64 + m], (1.f - z) * n + z * hold);
        }
        if (isFC && s >= 2 && s <= 513 && v == 2) {
            float p = 0.f;
            #pragma unroll
            for (int u = 0; u < 8; ++u) p += pl2[u * 64 + m];
            cstore(&apre_g[(s & 1) * 1024 + (w - 8) * 64 + m], p);
        }
        if (s == 514) break;
        // ---- grid barrier: counter tree, no fences (data is coherent) ----
        __syncthreads();                 // compiler drains vmcnt before s_barrier
        if (tid == 0) {
            const unsigned gen = (unsigned)(s + 1);
            unsigned p = __hip_atomic_fetch_add(&bar[(w >> 4) * 16], 1u,
                                                __ATOMIC_RELAXED, __HIP_MEMORY_SCOPE_AGENT);
            if (p + 1u == 16u * gen) {
                unsigned q = __hip_atomic_fetch_add(&bar[272], 1u,
                                                    __ATOMIC_RELAXED, __HIP_MEMORY_SCOPE_AGENT);
                if (q + 1u == 16u * gen)
                    __hip_atomic_store(&bar[288], gen,
                                       __ATOMIC_RELAXED, __HIP_MEMORY_SCOPE_AGENT);
            }
            unsigned f;
            do {
                f = __hip_atomic_load(&bar[288], __ATOMIC_RELAXED,
                                      __HIP_MEMORY_SCOPE_AGENT);
                if (f < gen) __builtin_amdgcn_s_sleep(8);
            } while (f < gen);
        }
        __syncthreads();
    }
}

// ---------------------------------------------------------------------------
extern "C" void kernel_launch(void* const* d_in, const int* in_sizes, int n_in,
                              void* d_out, int out_size, void* d_ws, size_t ws_size,
                              hipStream_t stream) {
    const float* x     = (const float*)d_in[0];
    const float* W_ih0 = (const float*)d_in[1];
    const float* W_hh0 = (const float*)d_in[2];
    const float* b_ih0 = (const float*)d_in[3];
    const float* b_hh0 = (const float*)d_in[4];
    const float* W_ih1 = (const float*)d_in[5];
    const float* W_hh1 = (const float*)d_in[6];
    const float* b_ih1 = (const float*)d_in[7];
    const float* b_hh1 = (const float*)d_in[8];
    const float* fc_W  = (const float*)d_in[9];
    const float* fc_b  = (const float*)d_in[10];
    const float* h0    = (const float*)d_in[11];
    const float* th0   = (const float*)d_in[12];
    const float* om0   = (const float*)d_in[13];
    float* out = (float*)d_out;

    float* ws = (float*)d_ws;
    float* h0buf  = ws;                 // 2 x [512][64] k-major parity buffers
    float* h1buf  = h0buf + 65536;
    float* apre_g = h1buf + 65536;      // 2 x [16][64]
    unsigned* bar = (unsigned*)(apre_g + 2048);    // 512 uints
    float* xT     = (float*)(bar + 512);           // [512][64][16]

    k_zero<<<2, 256, 0, stream>>>(bar, 512);
    k_xt<<<512, 256, 0, stream>>>(x, xT);

    void* args[] = {(void*)&xT, (void*)&W_ih0, (void*)&W_hh0, (void*)&b_ih0,
                    (void*)&b_hh0, (void*)&W_ih1, (void*)&W_hh1, (void*)&b_ih1,
                    (void*)&b_hh1, (void*)&fc_W, (void*)&fc_b, (void*)&h0,
                    (void*)&th0, (void*)&om0, (void*)&out, (void*)&h0buf,
                    (void*)&h1buf, (void*)&apre_g, (void*)&bar};
    (void)hipLaunchCooperativeKernel((void*)k_fused, dim3(NWG), dim3(NTH),
                                     args, 0, stream);
}

// Round 8
// 5962.714 us; speedup vs baseline: 12.9622x; 12.9622x over previous
//
#include <hip/hip_runtime.h>
#include <math.h>

#define NWG 256
#define NTH 512

// agent-coherent (L2-bypassing) scalar access — the cross-XCD exchange primitive
__device__ __forceinline__ float cload(const float* p) {
    return __hip_atomic_load(p, __ATOMIC_RELAXED, __HIP_MEMORY_SCOPE_AGENT);
}
__device__ __forceinline__ void cstore(float* p, float v) {
    __hip_atomic_store(p, v, __ATOMIC_RELAXED, __HIP_MEMORY_SCOPE_AGENT);
}

__global__ void k_zero(unsigned* p, int n) {
    int i = blockIdx.x * 256 + threadIdx.x;
    if (i < n) p[i] = 0u;
}

// transpose x [64][512][16] -> xT [512][64][16] (float4 granularity)
__global__ void k_xt(const float* __restrict__ x, float* __restrict__ xT) {
    int i = blockIdx.x * 256 + threadIdx.x;
    if (i < 131072) {
        int mt = i >> 2, q = i & 3;
        int m = mt >> 9, t = mt & 511;
        float4 v = *(const float4*)(x + (size_t)i * 4);
        *(float4*)(xT + ((size_t)t * 64 + m) * 16 + q * 4) = v;
    }
}

// One persistent cooperative kernel. WG w owns h-columns c0=2w, c0+1 of BOTH
// layers (6 gate-rows per matrix), lane = chain. Pipeline at slot s:
//   h0(s) | gi1(s-1)+h1(s-1) | FC(s-2) | biophys -> theta(s-3)
// h buffers: k-major [k][chain] parity double-buffers, agent-coherent access.
// ANTI-SPILL: __launch_bounds__(512,2) -> 256 VGPR cap (was 128: every round
// R4-R7 spilled the unrolled loop working set to scratch = 100-150 GB of
// WRITE traffic). kb loops kept at unroll 1 so the live set is one 16-chunk.
__global__ __launch_bounds__(NTH, 2)
void k_fused(const float* __restrict__ xT,
             const float* __restrict__ Wih0, const float* __restrict__ Whh0,
             const float* __restrict__ bih0, const float* __restrict__ bhh0,
             const float* __restrict__ Wih1, const float* __restrict__ Whh1,
             const float* __restrict__ bih1, const float* __restrict__ bhh1,
             const float* __restrict__ fcW, const float* __restrict__ fcb,
             const float* __restrict__ h0in, const float* __restrict__ th0,
             const float* __restrict__ om0, float* __restrict__ out,
             float* __restrict__ h0buf, float* __restrict__ h1buf,
             float* __restrict__ apre_g, unsigned* __restrict__ bar)
{
    const int w = blockIdx.x, tid = threadIdx.x;
    const int v = tid >> 6, m = tid & 63;
    const int c0 = w * 2;
    const int ks = v * 64;
    __shared__ float w0s[6 * 512];   // Whh0 rows (local g = gate*2 + j)
    __shared__ float wi1s[6 * 512];  // Wih1 rows
    __shared__ float w1s[6 * 512];   // Whh1 rows
    __shared__ float wihs[6 * 16];   // Wih0 rows
    __shared__ float fcrow[512];     // this WG's fc row (WGs 8..23)
    __shared__ float pl[8 * 12 * 64];
    __shared__ float pl2[8 * 64];

    for (int i = tid; i < 6 * 128; i += NTH) {
        int g = i >> 7, q = (i & 127) * 4;
        int row = (g >> 1) * 512 + c0 + (g & 1);
        *(float4*)&w0s[g * 512 + q]  = *(const float4*)(Whh0 + (size_t)row * 512 + q);
        *(float4*)&wi1s[g * 512 + q] = *(const float4*)(Wih1 + (size_t)row * 512 + q);
        *(float4*)&w1s[g * 512 + q]  = *(const float4*)(Whh1 + (size_t)row * 512 + q);
    }
    if (tid < 24) {
        int g = tid >> 2, q = (tid & 3) * 4;
        int row = (g >> 1) * 512 + c0 + (g & 1);
        *(float4*)&wihs[g * 16 + q] = *(const float4*)(Wih0 + (size_t)row * 16 + q);
    }
    const bool isFC = (w >= 8 && w < 24);
    if (isFC && tid < 128)
        *(float4*)&fcrow[tid * 4] = *(const float4*)(fcW + (size_t)(w - 8) * 512 + tid * 4);

    float b_r0=0,b_z0=0,b_in0=0,b_hn0=0, bi1r=0,bi1z=0,bi1n=0, bh1r=0,bh1z=0,bh1n=0;
    if (v < 2) {
        int c = c0 + v;
        b_r0  = bih0[c] + bhh0[c];
        b_z0  = bih0[512 + c] + bhh0[512 + c];
        b_in0 = bih0[1024 + c]; b_hn0 = bhh0[1024 + c];
        bi1r = bih1[c]; bi1z = bih1[512 + c]; bi1n = bih1[1024 + c];
        bh1r = bhh1[c]; bh1z = bhh1[512 + c]; bh1n = bhh1[1024 + c];
    }
    // biophys state: WG 0, thread = chain*8 + joint
    float th = 0.f, om = 0.f, fb0 = 0.f, fb1 = 0.f;
    if (w == 0) {
        th = th0[tid]; om = om0[tid];
        fb0 = fcb[2 * (tid & 7)]; fb1 = fcb[2 * (tid & 7) + 1];
    }
    const float* h1in = h0in + 32768;
    float gi_r = 0.f, gi_z = 0.f, gi_n = 0.f;
    __syncthreads();

    for (int s = 0; s < 515; ++s) {
        const int pw0 = s & 1, pr0 = (s + 1) & 1;
        // ---- biophys: consume apre written last slot -> theta(s-3) ----
        if (w == 0 && s >= 3) {
            int mc = tid >> 3, j = tid & 7;
            const float* ap = apre_g + ((s + 1) & 1) * 1024;
            float a0 = 1.f / (1.f + expf(-(cload(&ap[(2 * j) * 64 + mc]) + fb0)));
            float a1 = 1.f / (1.f + expf(-(cload(&ap[(2 * j + 1) * 64 + mc]) + fb1)));
            float F0 = (100.f + 2000.f * a0) * (0.06f + 0.006f * a0 + 0.05f * th);
            float F1 = (100.f + 2000.f * a1) * (0.06f + 0.006f * a1 - 0.05f * th);
            float tau = 0.05f * (F1 - F0);
            float acc = (tau - 5.f * th - 0.3f * om) * 250.f;
            om += (1.f / 60.f) * acc;
            th += (1.f / 60.f) * om;
            out[((size_t)mc * 512 + (s - 3)) * 8 + j] = th;
        }
        // ---- fused phase 1+2: Whh0 & Wih1 dots over h0(s-1) ----
        if (s <= 512) {
            float a01[12];
            #pragma unroll
            for (int g = 0; g < 12; ++g) a01[g] = 0.f;
            #pragma unroll 1
            for (int kb = 0; kb < 4; ++kb) {
                float hb[16];
                if (s == 0) {
                    #pragma unroll
                    for (int q = 0; q < 4; ++q) {
                        float4 t = *(const float4*)(h0in + (size_t)m * 512 + ks + kb * 16 + q * 4);
                        hb[q*4] = t.x; hb[q*4+1] = t.y; hb[q*4+2] = t.z; hb[q*4+3] = t.w;
                    }
                } else {
                    const float* hp = h0buf + pr0 * 32768 + (ks + kb * 16) * 64 + m;
                    #pragma unroll
                    for (int i = 0; i < 16; ++i) hb[i] = cload(&hp[i * 64]);
                }
                #pragma unroll
                for (int i = 0; i < 16; ++i) {
                    float hv = hb[i];
                    int ko = ks + kb * 16 + i;
                    #pragma unroll
                    for (int g = 0; g < 6; ++g) {
                        a01[g]     += w0s[g * 512 + ko] * hv;
                        a01[6 + g] += wi1s[g * 512 + ko] * hv;
                    }
                }
            }
            #pragma unroll
            for (int g = 0; g < 12; ++g) pl[(v * 12 + g) * 64 + m] = a01[g];
        }
        __syncthreads();
        // ---- combine A: h0(s) update + gi1(s-1) registers ----
        if (v < 2) {
            int c = c0 + v;
            if (s <= 511) {
                float hr = 0.f, hz = 0.f, hn = 0.f;
                #pragma unroll
                for (int u = 0; u < 8; ++u) {
                    hr += pl[(u * 12 + v) * 64 + m];
                    hz += pl[(u * 12 + 2 + v) * 64 + m];
                    hn += pl[(u * 12 + 4 + v) * 64 + m];
                }
                const float* xp = xT + ((size_t)s * 64 + m) * 16;
                float ir = 0.f, iz = 0.f, in_ = 0.f;
                #pragma unroll
                for (int k = 0; k < 16; ++k) {
                    float xv = xp[k];
                    ir  += wihs[v * 16 + k] * xv;
                    iz  += wihs[(2 + v) * 16 + k] * xv;
                    in_ += wihs[(4 + v) * 16 + k] * xv;
                }
                float hold = (s == 0) ? h0in[(size_t)m * 512 + c]
                                      : cload(&h0buf[pr0 * 32768 + c * 64 + m]);
                float r = 1.f / (1.f + expf(-(ir + hr + b_r0)));
                float z = 1.f / (1.f + expf(-(iz + hz + b_z0)));
                float n = tanhf(in_ + b_in0 + r * (hn + b_hn0));
                cstore(&h0buf[pw0 * 32768 + c * 64 + m], (1.f - z) * n + z * hold);
            }
            if (s >= 1 && s <= 512) {
                gi_r = bi1r; gi_z = bi1z; gi_n = bi1n;
                #pragma unroll
                for (int u = 0; u < 8; ++u) {
                    gi_r += pl[(u * 12 + 6 + v) * 64 + m];
                    gi_z += pl[(u * 12 + 8 + v) * 64 + m];
                    gi_n += pl[(u * 12 + 10 + v) * 64 + m];
                }
            }
        }
        __syncthreads();
        // ---- phase 3: Whh1 dot over h1(s-2) + FC dot, streamed in 16-chunks ----
        if (s >= 1 && s <= 513) {
            float a2[6];
            #pragma unroll
            for (int g = 0; g < 6; ++g) a2[g] = 0.f;
            float fdot = 0.f;
            #pragma unroll 1
            for (int kb = 0; kb < 4; ++kb) {
                float hb[16];
                if (s == 1) {
                    #pragma unroll
                    for (int q = 0; q < 4; ++q) {
                        float4 t = *(const float4*)(h1in + (size_t)m * 512 + ks + kb * 16 + q * 4);
                        hb[q*4] = t.x; hb[q*4+1] = t.y; hb[q*4+2] = t.z; hb[q*4+3] = t.w;
                    }
                } else {
                    const float* hp = h1buf + (s & 1) * 32768 + (ks + kb * 16) * 64 + m;
                    #pragma unroll
                    for (int i = 0; i < 16; ++i) hb[i] = cload(&hp[i * 64]);
                }
                #pragma unroll
                for (int i = 0; i < 16; ++i) {
                    float hv = hb[i];
                    int ko = ks + kb * 16 + i;
                    #pragma unroll
                    for (int g = 0; g < 6; ++g) a2[g] += w1s[g * 512 + ko] * hv;
                    fdot += hv * fcrow[ko];
                }
            }
            if (s <= 512) {
                #pragma unroll
                for (int g = 0; g < 6; ++g) pl[(v * 12 + g) * 64 + m] = a2[g];
            }
            if (isFC && s >= 2) pl2[v * 64 + m] = fdot;
        }
        __syncthreads();
        // ---- combine B: h1(s-1) update ----
        if (s >= 1 && s <= 512 && v < 2) {
            int c = c0 + v;
            float hr = 0.f, hz = 0.f, hn = 0.f;
            #pragma unroll
            for (int u = 0; u < 8; ++u) {
                hr += pl[(u * 12 + v) * 64 + m];
                hz += pl[(u * 12 + 2 + v) * 64 + m];
                hn += pl[(u * 12 + 4 + v) * 64 + m];
            }
            float hold = (s == 1) ? h1in[(size_t)m * 512 + c]
                                  : cload(&h1buf[(s & 1) * 32768 + c * 64 + m]);
            float r = 1.f / (1.f + expf(-(gi_r + hr + bh1r)));
            float z = 1.f / (1.f + expf(-(gi_z + hz + bh1z)));
            float n = tanhf(gi_n + r * (hn + bh1n));
            cstore(&h1buf[((s + 1) & 1) * 32768 + c * 64 + m], (1.f - z) * n + z * hold);
        }
        if (isFC && s >= 2 && s <= 513 && v == 2) {
            float p = 0.f;
            #pragma unroll
            for (int u = 0; u < 8; ++u) p += pl2[u * 64 + m];
            cstore(&apre_g[(s & 1) * 1024 + (w - 8) * 64 + m], p);
        }
        if (s == 514) break;
        // ---- grid barrier: counter tree, no fences (data is coherent) ----
        __syncthreads();                 // compiler drains vmcnt before s_barrier
        if (tid == 0) {
            const unsigned gen = (unsigned)(s + 1);
            unsigned p = __hip_atomic_fetch_add(&bar[(w >> 4) * 16], 1u,
                                                __ATOMIC_RELAXED, __HIP_MEMORY_SCOPE_AGENT);
            if (p + 1u == 16u * gen) {
                unsigned q = __hip_atomic_fetch_add(&bar[272], 1u,
                                                    __ATOMIC_RELAXED, __HIP_MEMORY_SCOPE_AGENT);
                if (q + 1u == 16u * gen)
                    __hip_atomic_store(&bar[288], gen,
                                       __ATOMIC_RELAXED, __HIP_MEMORY_SCOPE_AGENT);
            }
            unsigned f;
            do {
                f = __hip_atomic_load(&bar[288], __ATOMIC_RELAXED,
                                      __HIP_MEMORY_SCOPE_AGENT);
                if (f < gen) __builtin_amdgcn_s_sleep(8);
            } while (f < gen);
        }
        __syncthreads();
    }
}

// ---------------------------------------------------------------------------
extern "C" void kernel_launch(void* const* d_in, const int* in_sizes, int n_in,
                              void* d_out, int out_size, void* d_ws, size_t ws_size,
                              hipStream_t stream) {
    const float* x     = (const float*)d_in[0];
    const float* W_ih0 = (const float*)d_in[1];
    const float* W_hh0 = (const float*)d_in[2];
    const float* b_ih0 = (const float*)d_in[3];
    const float* b_hh0 = (const float*)d_in[4];
    const float* W_ih1 = (const float*)d_in[5];
    const float* W_hh1 = (const float*)d_in[6];
    const float* b_ih1 = (const float*)d_in[7];
    const float* b_hh1 = (const float*)d_in[8];
    const float* fc_W  = (const float*)d_in[9];
    const float* fc_b  = (const float*)d_in[10];
    const float* h0    = (const float*)d_in[11];
    const float* th0   = (const float*)d_in[12];
    const float* om0   = (const float*)d_in[13];
    float* out = (float*)d_out;

    float* ws = (float*)d_ws;
    float* h0buf  = ws;                 // 2 x [512][64] k-major parity buffers
    float* h1buf  = h0buf + 65536;
    float* apre_g = h1buf + 65536;      // 2 x [16][64]
    unsigned* bar = (unsigned*)(apre_g + 2048);    // 512 uints
    float* xT     = (float*)(bar + 512);           // [512][64][16]

    k_zero<<<2, 256, 0, stream>>>(bar, 512);
    k_xt<<<512, 256, 0, stream>>>(x, xT);

    void* args[] = {(void*)&xT, (void*)&W_ih0, (void*)&W_hh0, (void*)&b_ih0,
                    (void*)&b_hh0, (void*)&W_ih1, (void*)&W_hh1, (void*)&b_ih1,
                    (void*)&b_hh1, (void*)&fc_W, (void*)&fc_b, (void*)&h0,
                    (void*)&th0, (void*)&om0, (void*)&out, (void*)&h0buf,
                    (void*)&h1buf, (void*)&apre_g, (void*)&bar};
    (void)hipLaunchCooperativeKernel((void*)k_fused, dim3(NWG), dim3(NTH),
                                     args, 0, stream);
}